// Round 3
// baseline (722972.119 us; speedup 1.0000x reference)
//
#include <hip/hip_runtime.h>
#include <stdint.h>

// Problem dims
#define TS  256
#define CTS 512
#define BB  64
#define HH  512
#define KK  10

typedef short short8 __attribute__((ext_vector_type(8)));
typedef float floatx4 __attribute__((ext_vector_type(4)));

__device__ __forceinline__ unsigned short f2bf(float f) {
  unsigned u = __float_as_uint(f);
  unsigned r = (u + 0x7fffu + ((u >> 16) & 1u)) >> 16;  // RNE
  return (unsigned short)r;
}

// ---------------------------------------------------------------------------
// K1: cast W_ih and W_hh ([3H,H] f32, gate order r,z,n) to bf16.
__global__ void k_cast(const float* __restrict__ W_ih, const float* __restrict__ W_hh,
                       unsigned short* __restrict__ Wihb, unsigned short* __restrict__ Whhb) {
  int idx = blockIdx.x * 256 + threadIdx.x;  // 1536*512 total
  Wihb[idx] = f2bf(W_ih[idx]);
  Whhb[idx] = f2bf(W_hh[idx]);
}

// ---------------------------------------------------------------------------
// K2: G[t*64+b][30] = exp(x_t[b] @ {Wa;Wb;Wk}.T + bias). One wave per (t,b) row.
__global__ void k_abk(const float* __restrict__ inp,
                      const float* __restrict__ Wa, const float* __restrict__ ba,
                      const float* __restrict__ Wb, const float* __restrict__ bvb,
                      const float* __restrict__ Wk, const float* __restrict__ bk,
                      float* __restrict__ G) {
  int row = blockIdx.x;                 // t*64 + b
  int lane = threadIdx.x;               // 0..63
  int j = lane & 31, half = lane >> 5;  // j = output idx, half = K-half
  const float* Wrow; float bias;
  if (j < 10)      { Wrow = Wa + j * 512;        bias = ba[j]; }
  else if (j < 20) { Wrow = Wb + (j - 10) * 512; bias = bvb[j - 10]; }
  else if (j < 30) { Wrow = Wk + (j - 20) * 512; bias = bk[j - 20]; }
  else             { Wrow = Wa;                  bias = 0.f; }
  const float4* x4 = (const float4*)(inp + row * 512 + half * 256);
  const float4* w4 = (const float4*)(Wrow + half * 256);
  float acc = 0.f;
#pragma unroll 8
  for (int i = 0; i < 64; ++i) {
    float4 a = x4[i], w = w4[i];
    acc += a.x * w.x + a.y * w.y + a.z * w.z + a.w * w.w;
  }
  acc += __shfl_down(acc, 32, 64);  // fold the two K-halves
  if (lane < 30) G[row * 30 + lane] = __expf(acc + bias);
}

// ---------------------------------------------------------------------------
// K3: k_t cumsum over t for each (b,k) — parallel Hillis-Steele scan per b.
__global__ __launch_bounds__(256) void k_cumsum(
    const float* __restrict__ G, const float* __restrict__ att_init,
    float* __restrict__ out_k) {
  int b = blockIdx.x;       // 64 blocks
  int t = threadIdx.x;      // 256 = TS
  __shared__ float sb[2][256];
  for (int k = 0; k < KK; ++k) {
    float v = G[(t * BB + b) * 30 + 20 + k];
    sb[0][t] = v;
    __syncthreads();
    int src = 0;
#pragma unroll
    for (int d = 1; d < 256; d <<= 1) {
      float add = (t >= d) ? sb[src][t - d] : 0.f;
      float cur = sb[src][t];
      __syncthreads();
      sb[1 - src][t] = cur + add;
      src = 1 - src;
      __syncthreads();
    }
    out_k[(t * BB + b) * KK + k] = att_init[b * KK + k] + sb[src][t];
    __syncthreads();
  }
}

// ---------------------------------------------------------------------------
// K4: phi[b][t][s] = sum_k a*exp(-b*(k_t - s)^2), stored bf16.
__global__ void k_phi(const float* __restrict__ G, const float* __restrict__ attk,
                      unsigned short* __restrict__ phi_bf) {
  int t = blockIdx.x, b = blockIdx.y;
  int row = t * BB + b;
  float a[10], bv[10], kt[10];
#pragma unroll
  for (int k = 0; k < 10; ++k) {
    a[k]  = G[row * 30 + k];
    bv[k] = G[row * 30 + 10 + k];
    kt[k] = attk[row * KK + k];
  }
#pragma unroll
  for (int e = 0; e < 2; ++e) {
    int s = threadIdx.x + e * 256;
    float fs = (float)s;
    float ph = 0.f;
#pragma unroll
    for (int k = 0; k < 10; ++k) {
      float d = kt[k] - fs;
      ph += a[k] * __expf(-bv[k] * d * d);
    }
    phi_bf[(b * TS + t) * CTS + s] = f2bf(ph);
  }
}

// ---------------------------------------------------------------------------
// K5: att_w[t][b][h] = sum_s phi[b][t][s] * c_inp[s][b][h]. Per-b MFMA GEMM.
// Writes f32 to out_w (final output) and bf16 to awb (k_seq's w-side operand).
__global__ __launch_bounds__(256) void k_attw(
    const float* __restrict__ c_inp, const unsigned short* __restrict__ phi_bf,
    float* __restrict__ out_w, unsigned short* __restrict__ attw_bf) {
  int h0 = blockIdx.x * 64;
  int t0 = blockIdx.y * 64;
  int b  = blockIdx.z;
  int tid = threadIdx.x;
  int lane = tid & 63, wv = tid >> 6;
  int x = lane & 15, q = lane >> 4;
  __shared__ __align__(16) unsigned short Bt[64 * 40];  // [h_local][s_local], pad 40
  floatx4 acc[4];
#pragma unroll
  for (int m = 0; m < 4; ++m) acc[m] = (floatx4){0.f, 0.f, 0.f, 0.f};
  int s_l = tid >> 3, h8 = (tid & 7) * 8;
  for (int ss = 0; ss < 16; ++ss) {
    int s0 = ss * 32;
    const float* src = c_inp + ((s0 + s_l) * BB + b) * HH + h0 + h8;
    float4 v0 = *(const float4*)src;
    float4 v1 = *(const float4*)(src + 4);
    Bt[(h8 + 0) * 40 + s_l] = f2bf(v0.x);
    Bt[(h8 + 1) * 40 + s_l] = f2bf(v0.y);
    Bt[(h8 + 2) * 40 + s_l] = f2bf(v0.z);
    Bt[(h8 + 3) * 40 + s_l] = f2bf(v0.w);
    Bt[(h8 + 4) * 40 + s_l] = f2bf(v1.x);
    Bt[(h8 + 5) * 40 + s_l] = f2bf(v1.y);
    Bt[(h8 + 6) * 40 + s_l] = f2bf(v1.z);
    Bt[(h8 + 7) * 40 + s_l] = f2bf(v1.w);
    __syncthreads();
    short8 bfrag = *(const short8*)(Bt + (wv * 16 + x) * 40 + q * 8);
#pragma unroll
    for (int mt = 0; mt < 4; ++mt) {
      short8 af = *(const short8*)(phi_bf + (b * TS + t0 + mt * 16 + x) * CTS + s0 + q * 8);
      acc[mt] = __builtin_amdgcn_mfma_f32_16x16x32_bf16(af, bfrag, acc[mt], 0, 0, 0);
    }
    __syncthreads();
  }
#pragma unroll
  for (int mt = 0; mt < 4; ++mt)
#pragma unroll
    for (int r = 0; r < 4; ++r) {
      int t_l = mt * 16 + q * 4 + r;           // C/D: row = quad*4+reg
      int row = (t0 + t_l) * BB + b;
      int col = h0 + wv * 16 + x;              // C/D: col = lane&15
      float v = acc[mt][r];
      out_w[row * HH + col] = v;
      attw_bf[row * HH + col] = f2bf(v);
    }
}

// ---------------------------------------------------------------------------
// K6: persistent GRU. 32 worker WGs pinned to ONE XCD (h exchange via that
// XCD's L2). Batch dim split into 4 gangs of 16, one per wave: wave (w,wv)
// computes gates for b in [16wv,16wv+16), j in [16w,16w+16). Zero barriers
// in the loop; per-wave flags.
//   - w-side (attw @ W_ih): attw(t) A-frags prefetched into regs one step
//     ahead; W_ih B-frags in LDS (shared by the WG's 4 waves, conflict-free
//     frag-major layout). Runs BEFORE the h poll -> overlaps others' latency.
//   - h-side (h @ W_hh): W_hh B-frags register-resident; h A-frags loaded
//     straight from XCD L2 (sc0 dwordx4). Gates stay in the producing lane
//     (C/D row=q*4+r -> batch, col=x -> j).
// Four accumulators (r, z, n_w, n_h) since n = tanh(i_n + r*h_n).
#define WAITVM(N) asm volatile("s_waitcnt vmcnt(" #N ")" ::: "memory")
#define SFENCE() __builtin_amdgcn_sched_barrier(0)
#define LDA(k, off)                                                       \
  asm volatile("global_load_dwordx4 %0, %1, off offset:" #off " sc0"      \
               : "=v"(afr[k]) : "v"(hsrc) : "memory")
#define MF3H(k)                                                                        \
  ar_ = __builtin_amdgcn_mfma_f32_16x16x32_bf16(afr[k], wfrag[0][k], ar_, 0, 0, 0);    \
  az_ = __builtin_amdgcn_mfma_f32_16x16x32_bf16(afr[k], wfrag[1][k], az_, 0, 0, 0);    \
  nh_ = __builtin_amdgcn_mfma_f32_16x16x32_bf16(afr[k], wfrag[2][k], nh_, 0, 0, 0)

__global__ __launch_bounds__(256, 1) void k_seq(
    const unsigned short* __restrict__ awb, const unsigned short* __restrict__ Wihb,
    const unsigned short* __restrict__ Whhb, const float* __restrict__ gru_init,
    const float* __restrict__ b_ih, const float* __restrict__ b_hh,
    unsigned short* __restrict__ h_buf, unsigned* __restrict__ flags,
    unsigned* __restrict__ ctl, float* __restrict__ hid_out) {
  // 96 KB LDS: first 48 KB = W_ih fragments; total size forces 1 WG/CU so all
  // 256 WGs are co-resident (XCD-claim handshake needs it).
  __shared__ __align__(16) unsigned short Swih[49152];
  __shared__ int sh_slot;
  const int tid = threadIdx.x;

  // --- XCD-local slot discovery (device-scope atomics, one-time) ---
  if (tid == 0) {
    unsigned xcc = __builtin_amdgcn_s_getreg(6164) & 0xfu;  // hwreg(HW_REG_XCC_ID,0,4)
    unsigned s = atomicAdd(&ctl[1 + xcc], 1u);
    if (s == 31u) atomicCAS(&ctl[0], 0u, xcc + 1u);         // first full bucket wins
    unsigned ch; int spin = 0;
    do {
      ch = __hip_atomic_load(&ctl[0], __ATOMIC_RELAXED, __HIP_MEMORY_SCOPE_AGENT);
    } while (ch == 0u && ++spin < (1 << 22));
    sh_slot = (ch != 0u && ch - 1u == xcc && s < 32u) ? (int)s : -1;
  }
  __syncthreads();
  const int w = sh_slot;
  if (w < 0) return;  // not a worker

  const int lane = tid & 63, wv = tid >> 6;
  const int x = lane & 15, q = lane >> 4;
  const int j0 = w * 16;          // this WG's 16 h-columns
  const int b0 = wv * 16;         // this wave's gang: 16 batches
  const int bq = b0 + q * 4;      // C/D row base for this lane
  const int jx = j0 + x;
  const int fslot = (w * 4 + wv) * 8;

  // --- stage W_ih frags into LDS, frag-major: shortidx = fidx*8,
  //     fidx = ((g*16+kk)*4+q)*16 + jl. Read back conflict-free (1KB/frag-set).
#pragma unroll
  for (int i = 0; i < 12; ++i) {
    int fidx = i * 256 + tid;
    int jl = fidx & 15;
    int rest = fidx >> 4;          // (g*16+kk)*4+q
    int qq = rest & 3;
    int rest2 = rest >> 2;         // g*16+kk
    int kk = rest2 & 15, g = rest2 >> 4;
    *(short8*)(Swih + (size_t)fidx * 8) =
        *(const short8*)(Wihb + (size_t)(g * 512 + j0 + jl) * 512 + kk * 32 + qq * 8);
  }

  // --- W_hh B-frags into registers: rows g*512+jx, K cols kk*32+q*8 ---
  short8 wfrag[3][16];
#pragma unroll
  for (int g = 0; g < 3; ++g) {
    const unsigned short* wr = Whhb + (size_t)(g * 512 + jx) * 512 + q * 8;
#pragma unroll
    for (int kk = 0; kk < 16; ++kk)
      wfrag[g][kk] = *(const short8*)(wr + kk * 32);
  }
  const float biasR  = b_ih[jx] + b_hh[jx];
  const float biasZ  = b_ih[512 + jx] + b_hh[512 + jx];
  const float biasNW = b_ih[1024 + jx];
  const float biasNH = b_hh[1024 + jx];

  float hp[4];
#pragma unroll
  for (int r = 0; r < 4; ++r) hp[r] = gru_init[(size_t)(bq + r) * HH + jx];

  __syncthreads();  // Swih staged (last barrier in the kernel)

  // --- publish h_0 into slot 0 (plain stores -> XCD L2), then flag ---
#pragma unroll
  for (int r = 0; r < 4; ++r) {
    unsigned long long p =
        (unsigned long long)(uintptr_t)(h_buf + (size_t)(bq + r) * HH + jx);
    asm volatile("global_store_short %0, %1, off"
                 :: "v"(p), "v"((unsigned)f2bf(hp[r])) : "memory");
  }
  WAITVM(0);
  if (lane == 0) {
    unsigned long long p = (unsigned long long)(uintptr_t)(flags + fslot);
    asm volatile("global_store_dword %0, %1, off" :: "v"(p), "v"(1u) : "memory");
  }

  // --- attw(0) A-frags prefetch ---
  short8 afw[16];
  {
    const unsigned short* ap = awb + (size_t)(b0 + x) * HH + q * 8;
#pragma unroll
    for (int kk = 0; kk < 16; ++kk) afw[kk] = *(const short8*)(ap + kk * 32);
  }

#pragma unroll 1
  for (int t = 0; t < TS; ++t) {
    // --- [A] w-side GEMM (independent of h) + afw refill for t+1 ---
    floatx4 ar_ = {biasR, biasR, biasR, biasR};
    floatx4 az_ = {biasZ, biasZ, biasZ, biasZ};
    floatx4 nw_ = {biasNW, biasNW, biasNW, biasNW};
    floatx4 nh_ = {biasNH, biasNH, biasNH, biasNH};
    {
      int tn = (t + 1 < TS) ? t + 1 : t;
      const unsigned short* awn = awb + ((size_t)tn * BB + b0 + x) * HH + q * 8;
      const unsigned short* fb = Swih + (size_t)q * 128 + x * 8;
#pragma unroll
      for (int kk = 0; kk < 16; ++kk) {
        short8 a = afw[kk];
        ar_ = __builtin_amdgcn_mfma_f32_16x16x32_bf16(
            a, *(const short8*)(fb + kk * 512), ar_, 0, 0, 0);
        az_ = __builtin_amdgcn_mfma_f32_16x16x32_bf16(
            a, *(const short8*)(fb + kk * 512 + 8192), az_, 0, 0, 0);
        nw_ = __builtin_amdgcn_mfma_f32_16x16x32_bf16(
            a, *(const short8*)(fb + kk * 512 + 16384), nw_, 0, 0, 0);
        afw[kk] = *(const short8*)(awn + kk * 32);   // refill (consumed next step)
      }
    }

    // --- [B] wait for this gang's 32 producer waves to have published h_t ---
    if (lane < 32) {
      const unsigned* fp = flags + (lane * 4 + wv) * 8;
      unsigned fv; int spin = 0;
      do {
        asm volatile("global_load_dword %0, %1, off sc0\n\ts_waitcnt vmcnt(0)"
                     : "=v"(fv)
                     : "v"((unsigned long long)(uintptr_t)fp)
                     : "memory");
      } while (fv < (unsigned)(t + 1) && ++spin < (1 << 15));
    }

    // --- [C] h A-frags: gang's 16x512 h-slice from L2 into VGPRs ---
    const unsigned long long hsrc = (unsigned long long)(uintptr_t)(
        h_buf + (size_t)(t & 3) * (BB * HH) + (size_t)(b0 + x) * HH + q * 8);
    short8 afr[16];
    LDA(0, 0);   LDA(1, 64);  LDA(2, 128); LDA(3, 192);
    LDA(4, 256); LDA(5, 320); LDA(6, 384); LDA(7, 448);
    WAITVM(0);   // first 8 resident
    SFENCE();
    LDA(8, 512);  LDA(9, 576);  LDA(10, 640); LDA(11, 704);
    LDA(12, 768); LDA(13, 832); LDA(14, 896); LDA(15, 960);
    MF3H(0); MF3H(1); MF3H(2); MF3H(3); MF3H(4); MF3H(5); MF3H(6); MF3H(7);
    WAITVM(0);   // second 8 resident
    SFENCE();
    MF3H(8); MF3H(9); MF3H(10); MF3H(11); MF3H(12); MF3H(13); MF3H(14); MF3H(15);

    // --- [D] gates: everything for (b,j) lives in this lane ---
    float hn[4];
#pragma unroll
    for (int r = 0; r < 4; ++r) {
      float rr = 1.f / (1.f + __expf(-ar_[r]));
      float zz = 1.f / (1.f + __expf(-az_[r]));
      float e2 = __expf(2.f * (nw_[r] + rr * nh_[r]));
      float nn = 1.f - 2.f / (e2 + 1.f);          // tanh
      hn[r] = (1.f - zz) * nn + zz * hp[r];
    }

    // --- [E] publish h_{t+1}, drain, flag ---
    unsigned short* hdst = h_buf + (size_t)((t + 1) & 3) * (BB * HH);
#pragma unroll
    for (int r = 0; r < 4; ++r) {
      unsigned long long p =
          (unsigned long long)(uintptr_t)(hdst + (size_t)(bq + r) * HH + jx);
      asm volatile("global_store_short %0, %1, off"
                   :: "v"(p), "v"((unsigned)f2bf(hn[r])) : "memory");
    }
    WAITVM(0);
    if (lane == 0) {
      unsigned long long p = (unsigned long long)(uintptr_t)(flags + fslot);
      asm volatile("global_store_dword %0, %1, off"
                   :: "v"(p), "v"((unsigned)(t + 2)) : "memory");
    }

    // --- [F] f32 outputs (off the critical path, post-flag) ---
#pragma unroll
    for (int r = 0; r < 4; ++r)
      hid_out[((size_t)t * BB + bq + r) * HH + jx] = hn[r];
#pragma unroll
    for (int r = 0; r < 4; ++r) hp[r] = hn[r];
  }
}

// ---------------------------------------------------------------------------
// Workspace layout (39.1 MB total, NO aliasing — fits the proven 46.4 MB budget):
//   [0,        2MB)   G
//   [2MB,    3.5MB)   Wihb
//   [3.5MB,    5MB)   Whhb
//   [5MB,     21MB)   phi
//   [21MB,    37MB)   awb
//   [37MB, 37.25MB)   hbuf (4 ring slots)
//   [+4KB flags][+64B ctl]
extern "C" void kernel_launch(void* const* d_in, const int* in_sizes, int n_in,
                              void* d_out, int out_size, void* d_ws, size_t ws_size,
                              hipStream_t stream) {
  const float* c_inp    = (const float*)d_in[0];
  const float* inp      = (const float*)d_in[1];
  const float* gru_init = (const float*)d_in[2];
  const float* att_init = (const float*)d_in[3];
  const float* Wa = (const float*)d_in[4];
  const float* ba = (const float*)d_in[5];
  const float* Wb = (const float*)d_in[6];
  const float* bvb = (const float*)d_in[7];
  const float* Wk = (const float*)d_in[8];
  const float* bk = (const float*)d_in[9];
  const float* W_ih = (const float*)d_in[10];
  const float* b_ih = (const float*)d_in[11];
  const float* W_hh = (const float*)d_in[12];
  const float* b_hh = (const float*)d_in[13];

  float* out_h = (float*)d_out;                     // hiddens [256,64,512]
  float* out_k = out_h + TS * BB * HH;              // att_k   [256,64,10]
  float* out_w = out_k + TS * BB * KK;              // att_w   [256,64,512]

  char* ws = (char*)d_ws;
  float* G             = (float*)(ws);                          // 1.97 MB
  unsigned short* Wihb = (unsigned short*)(ws + 2097152);       // 1.5 MB
  unsigned short* Whhb = (unsigned short*)(ws + 3670016);       // 1.5 MB
  unsigned short* phi  = (unsigned short*)(ws + 5242880);       // 16 MB
  unsigned short* awb  = (unsigned short*)(ws + 22020096);      // 16 MB
  unsigned short* hbuf = (unsigned short*)(ws + 38797312);      // 256 KB (4 slots)
  unsigned* flags      = (unsigned*)(ws + 39059456);            // 4 KB
  unsigned* ctl        = (unsigned*)(ws + 39063552);            // 64 B

  hipMemsetAsync(flags, 0, 8192, stream);  // flags + ctl
  hipLaunchKernelGGL(k_cast, dim3(3072), dim3(256), 0, stream, W_ih, W_hh, Wihb, Whhb);
  hipLaunchKernelGGL(k_abk, dim3(TS * BB), dim3(64), 0, stream,
                     inp, Wa, ba, Wb, bvb, Wk, bk, G);
  hipLaunchKernelGGL(k_cumsum, dim3(BB), dim3(256), 0, stream, G, att_init, out_k);
  hipLaunchKernelGGL(k_phi, dim3(TS, BB), dim3(256), 0, stream, G, out_k, phi);
  hipLaunchKernelGGL(k_attw, dim3(8, 4, BB), dim3(256), 0, stream, c_inp, phi, out_w, awb);
  hipLaunchKernelGGL(k_seq, dim3(256), dim3(256), 0, stream,
                     awb, Wihb, Whhb, gru_init, b_ih, b_hh, hbuf, flags, ctl, out_h);
}

// Round 5
// 80789.136 us; speedup vs baseline: 8.9489x; 8.9489x over previous
//
#include <hip/hip_runtime.h>
#include <stdint.h>

// Problem dims
#define TS  256
#define CTS 512
#define BB  64
#define HH  512
#define KK  10

typedef short short8 __attribute__((ext_vector_type(8)));
typedef float floatx4 __attribute__((ext_vector_type(4)));

__device__ __forceinline__ unsigned short f2bf(float f) {
  unsigned u = __float_as_uint(f);
  unsigned r = (u + 0x7fffu + ((u >> 16) & 1u)) >> 16;  // RNE
  return (unsigned short)r;
}

// global -> LDS async, 16 B/lane. LDS dst = base + lane*16 (HW rule).
typedef __attribute__((address_space(1))) const unsigned int gas_u32;
typedef __attribute__((address_space(3))) unsigned int las_u32;
__device__ __forceinline__ void gll16_sc0(const void* g, void* l) { // bypass L1, read L2
  __builtin_amdgcn_global_load_lds((gas_u32*)g, (las_u32*)l, 16, 0, 1);
}

// ---------------------------------------------------------------------------
// K1: cast W_ih and W_hh ([3H,H] f32, gate order r,z,n) to bf16.
__global__ void k_cast(const float* __restrict__ W_ih, const float* __restrict__ W_hh,
                       unsigned short* __restrict__ Wihb, unsigned short* __restrict__ Whhb) {
  int idx = blockIdx.x * 256 + threadIdx.x;  // 1536*512 total
  Wihb[idx] = f2bf(W_ih[idx]);
  Whhb[idx] = f2bf(W_hh[idx]);
}

// ---------------------------------------------------------------------------
// K2: G[t*64+b][30] = exp(x_t[b] @ {Wa;Wb;Wk}.T + bias). One wave per (t,b) row.
__global__ void k_abk(const float* __restrict__ inp,
                      const float* __restrict__ Wa, const float* __restrict__ ba,
                      const float* __restrict__ Wb, const float* __restrict__ bvb,
                      const float* __restrict__ Wk, const float* __restrict__ bk,
                      float* __restrict__ G) {
  int row = blockIdx.x;                 // t*64 + b
  int lane = threadIdx.x;               // 0..63
  int j = lane & 31, half = lane >> 5;  // j = output idx, half = K-half
  const float* Wrow; float bias;
  if (j < 10)      { Wrow = Wa + j * 512;        bias = ba[j]; }
  else if (j < 20) { Wrow = Wb + (j - 10) * 512; bias = bvb[j - 10]; }
  else if (j < 30) { Wrow = Wk + (j - 20) * 512; bias = bk[j - 20]; }
  else             { Wrow = Wa;                  bias = 0.f; }
  const float4* x4 = (const float4*)(inp + row * 512 + half * 256);
  const float4* w4 = (const float4*)(Wrow + half * 256);
  float acc = 0.f;
#pragma unroll 8
  for (int i = 0; i < 64; ++i) {
    float4 a = x4[i], w = w4[i];
    acc += a.x * w.x + a.y * w.y + a.z * w.z + a.w * w.w;
  }
  acc += __shfl_down(acc, 32, 64);  // fold the two K-halves
  if (lane < 30) G[row * 30 + lane] = __expf(acc + bias);
}

// ---------------------------------------------------------------------------
// K3: k_t cumsum over t for each (b,k) — parallel Hillis-Steele scan per b.
__global__ __launch_bounds__(256) void k_cumsum(
    const float* __restrict__ G, const float* __restrict__ att_init,
    float* __restrict__ out_k) {
  int b = blockIdx.x;       // 64 blocks
  int t = threadIdx.x;      // 256 = TS
  __shared__ float sb[2][256];
  for (int k = 0; k < KK; ++k) {
    float v = G[(t * BB + b) * 30 + 20 + k];
    sb[0][t] = v;
    __syncthreads();
    int src = 0;
#pragma unroll
    for (int d = 1; d < 256; d <<= 1) {
      float add = (t >= d) ? sb[src][t - d] : 0.f;
      float cur = sb[src][t];
      __syncthreads();
      sb[1 - src][t] = cur + add;
      src = 1 - src;
      __syncthreads();
    }
    out_k[(t * BB + b) * KK + k] = att_init[b * KK + k] + sb[src][t];
    __syncthreads();
  }
}

// ---------------------------------------------------------------------------
// K4: phi[b][t][s] = sum_k a*exp(-b*(k_t - s)^2), stored bf16.
__global__ void k_phi(const float* __restrict__ G, const float* __restrict__ attk,
                      unsigned short* __restrict__ phi_bf) {
  int t = blockIdx.x, b = blockIdx.y;
  int row = t * BB + b;
  float a[10], bv[10], kt[10];
#pragma unroll
  for (int k = 0; k < 10; ++k) {
    a[k]  = G[row * 30 + k];
    bv[k] = G[row * 30 + 10 + k];
    kt[k] = attk[row * KK + k];
  }
#pragma unroll
  for (int e = 0; e < 2; ++e) {
    int s = threadIdx.x + e * 256;
    float fs = (float)s;
    float ph = 0.f;
#pragma unroll
    for (int k = 0; k < 10; ++k) {
      float d = kt[k] - fs;
      ph += a[k] * __expf(-bv[k] * d * d);
    }
    phi_bf[(b * TS + t) * CTS + s] = f2bf(ph);
  }
}

// ---------------------------------------------------------------------------
// K5: att_w[t][b][h] = sum_s phi[b][t][s] * c_inp[s][b][h]. Per-b MFMA GEMM.
// Writes f32 to out_w (final output) and bf16 to awb (k_seq's w-side operand).
__global__ __launch_bounds__(256) void k_attw(
    const float* __restrict__ c_inp, const unsigned short* __restrict__ phi_bf,
    float* __restrict__ out_w, unsigned short* __restrict__ attw_bf) {
  int h0 = blockIdx.x * 64;
  int t0 = blockIdx.y * 64;
  int b  = blockIdx.z;
  int tid = threadIdx.x;
  int lane = tid & 63, wv = tid >> 6;
  int x = lane & 15, q = lane >> 4;
  __shared__ __align__(16) unsigned short Bt[64 * 40];  // [h_local][s_local], pad 40
  floatx4 acc[4];
#pragma unroll
  for (int m = 0; m < 4; ++m) acc[m] = (floatx4){0.f, 0.f, 0.f, 0.f};
  int s_l = tid >> 3, h8 = (tid & 7) * 8;
  for (int ss = 0; ss < 16; ++ss) {
    int s0 = ss * 32;
    const float* src = c_inp + ((s0 + s_l) * BB + b) * HH + h0 + h8;
    float4 v0 = *(const float4*)src;
    float4 v1 = *(const float4*)(src + 4);
    Bt[(h8 + 0) * 40 + s_l] = f2bf(v0.x);
    Bt[(h8 + 1) * 40 + s_l] = f2bf(v0.y);
    Bt[(h8 + 2) * 40 + s_l] = f2bf(v0.z);
    Bt[(h8 + 3) * 40 + s_l] = f2bf(v0.w);
    Bt[(h8 + 4) * 40 + s_l] = f2bf(v1.x);
    Bt[(h8 + 5) * 40 + s_l] = f2bf(v1.y);
    Bt[(h8 + 6) * 40 + s_l] = f2bf(v1.z);
    Bt[(h8 + 7) * 40 + s_l] = f2bf(v1.w);
    __syncthreads();
    short8 bfrag = *(const short8*)(Bt + (wv * 16 + x) * 40 + q * 8);
#pragma unroll
    for (int mt = 0; mt < 4; ++mt) {
      short8 af = *(const short8*)(phi_bf + (b * TS + t0 + mt * 16 + x) * CTS + s0 + q * 8);
      acc[mt] = __builtin_amdgcn_mfma_f32_16x16x32_bf16(af, bfrag, acc[mt], 0, 0, 0);
    }
    __syncthreads();
  }
#pragma unroll
  for (int mt = 0; mt < 4; ++mt)
#pragma unroll
    for (int r = 0; r < 4; ++r) {
      int t_l = mt * 16 + q * 4 + r;           // C/D: row = quad*4+reg
      int row = (t0 + t_l) * BB + b;
      int col = h0 + wv * 16 + x;              // C/D: col = lane&15
      float v = acc[mt][r];
      out_w[row * HH + col] = v;
      attw_bf[row * HH + col] = f2bf(v);
    }
}

// ---------------------------------------------------------------------------
// K6: persistent GRU. 32 worker WGs pinned to ONE XCD. Gang decomposition
// (round-3-verified compute): wave (w,wv) -> b in [16wv,16wv+16),
// j in [16w,16w+16), gates in-lane (C/D row=q*4+r -> batch, col=x -> j).
// Cross-WG edges rebuilt from round-0-proven parts:
//   - h staging: gll16 sc0 -> hsT LDS tile (XOR-swizzled), s_waitcnt(0)+barrier
//   - h publish: plain C++ packed-dword stores (shfl-paired lanes)
//   - flag: agent-scope RELEASE atomic store (>= round-0's plain store)
//   - poll: round-0 asm sc0 loop, bounded 4096 (graceful timeout, counters
//     survive; round 3 proved correctness holds under timeout)
// w-side (attw @ W_ih, h-independent) runs BEFORE the poll: W_ih frags in
// 48 KB LDS (round-3 layout), attw A-frags reg-prefetched one step ahead.
// h-side W_hh frags register/AGPR-resident. 3 barriers/step, no gbuf.
#define WAITVM(N) asm volatile("s_waitcnt vmcnt(" #N ")" ::: "memory")

__global__ __launch_bounds__(256, 1) void k_seq(
    const unsigned short* __restrict__ awb, const unsigned short* __restrict__ Wihb,
    const unsigned short* __restrict__ Whhb, const float* __restrict__ gru_init,
    const float* __restrict__ b_ih, const float* __restrict__ b_hh,
    unsigned short* __restrict__ h_buf, unsigned* __restrict__ flags,
    unsigned* __restrict__ ctl, float* __restrict__ hid_out) {
  // 112 KB LDS -> 1 WG/CU so all 256 WGs co-reside (handshake needs it).
  __shared__ __align__(16) unsigned short Swih[24576];  // 48 KB W_ih frags
  __shared__ __align__(16) unsigned short hsT[64 * 512];  // 64 KB h tile (swizzled)
  __shared__ int sh_slot;
  const int tid = threadIdx.x;

  // --- XCD-local slot discovery (device-scope atomics, one-time) ---
  if (tid == 0) {
    unsigned xcc = __builtin_amdgcn_s_getreg(6164) & 0xfu;  // hwreg(HW_REG_XCC_ID,0,4)
    unsigned s = atomicAdd(&ctl[1 + xcc], 1u);
    if (s == 31u) atomicCAS(&ctl[0], 0u, xcc + 1u);         // first full bucket wins
    unsigned ch; int spin = 0;
    do {
      ch = __hip_atomic_load(&ctl[0], __ATOMIC_RELAXED, __HIP_MEMORY_SCOPE_AGENT);
    } while (ch == 0u && ++spin < (1 << 22));
    sh_slot = (ch != 0u && ch - 1u == xcc && s < 32u) ? (int)s : -1;
  }
  __syncthreads();
  const int w = sh_slot;
  if (w < 0) return;  // not a worker

  const int lane = tid & 63, wv = tid >> 6;
  const int x = lane & 15, q = lane >> 4;
  const int j0 = w * 16;          // this WG's 16 h-columns
  const int b0 = wv * 16;         // this wave's gang: 16 batches
  const int bq = b0 + q * 4;      // C/D row base for this lane
  const int jx = j0 + x;

  // --- stage W_ih frags into LDS, frag-major (round-3-verified layout):
  //     short addr = fidx*8, fidx = ((g*16+kk)*4+q)*16 + jl.
#pragma unroll
  for (int i = 0; i < 12; ++i) {
    int fidx = i * 256 + tid;          // 0..3071
    int jl = fidx & 15;
    int rest = fidx >> 4;              // (g*16+kk)*4+q
    int qq = rest & 3;
    int rest2 = rest >> 2;             // g*16+kk
    int kk = rest2 & 15, g = rest2 >> 4;
    *(short8*)(Swih + (size_t)fidx * 8) =
        *(const short8*)(Wihb + (size_t)(g * 512 + j0 + jl) * 512 + kk * 32 + qq * 8);
  }

  // --- W_hh B-frags into registers/AGPRs: rows g*512+jx, K cols kk*32+q*8 ---
  short8 wfrag[3][16];
#pragma unroll
  for (int g = 0; g < 3; ++g) {
    const unsigned short* wr = Whhb + (size_t)(g * 512 + jx) * 512 + q * 8;
#pragma unroll
    for (int kk = 0; kk < 16; ++kk)
      wfrag[g][kk] = *(const short8*)(wr + kk * 32);
  }
  const float biasR  = b_ih[jx] + b_hh[jx];
  const float biasZ  = b_ih[512 + jx] + b_hh[512 + jx];
  const float biasNW = b_ih[1024 + jx];
  const float biasNH = b_hh[1024 + jx];

  float hp[4];
#pragma unroll
  for (int r = 0; r < 4; ++r) hp[r] = gru_init[(size_t)(bq + r) * HH + jx];

  // --- publish h_0 (packed C++ dword stores; even-x lanes write j,j+1) ---
#pragma unroll
  for (int r = 0; r < 4; ++r) {
    float ov = __shfl(hp[r], lane ^ 1, 64);
    if ((x & 1) == 0)
      *(unsigned*)(h_buf + (size_t)(bq + r) * HH + jx) =
          (unsigned)f2bf(hp[r]) | ((unsigned)f2bf(ov) << 16);
  }
  WAITVM(0);
  __syncthreads();                 // h_0 drained by ALL waves; Swih staged
  if (tid == 0)
    __hip_atomic_store(&flags[w * 32], 1u, __ATOMIC_RELEASE, __HIP_MEMORY_SCOPE_AGENT);
  asm volatile("" ::: "memory");

  // --- attw(0) A-frags prefetch ---
  short8 afw[16];
  {
    const unsigned short* ap = awb + (size_t)(b0 + x) * HH + q * 8;
#pragma unroll
    for (int kk = 0; kk < 16; ++kk) afw[kk] = *(const short8*)(ap + kk * 32);
  }

#pragma unroll 1
  for (int t = 0; t < TS; ++t) {
    // --- [A] w-side GEMM (h-independent) + afw refill for t+1 ---
    floatx4 ar_ = {biasR, biasR, biasR, biasR};
    floatx4 az_ = {biasZ, biasZ, biasZ, biasZ};
    floatx4 nw_ = {biasNW, biasNW, biasNW, biasNW};
    floatx4 nh_ = {biasNH, biasNH, biasNH, biasNH};
    {
      int tn = (t + 1 < TS) ? t + 1 : t;
      const unsigned short* awn = awb + ((size_t)tn * BB + b0 + x) * HH + q * 8;
      const unsigned short* fb = Swih + (size_t)q * 128 + x * 8;
#pragma unroll
      for (int kk = 0; kk < 16; ++kk) {
        short8 a = afw[kk];
        ar_ = __builtin_amdgcn_mfma_f32_16x16x32_bf16(
            a, *(const short8*)(fb + kk * 512), ar_, 0, 0, 0);
        az_ = __builtin_amdgcn_mfma_f32_16x16x32_bf16(
            a, *(const short8*)(fb + kk * 512 + 8192), az_, 0, 0, 0);
        nw_ = __builtin_amdgcn_mfma_f32_16x16x32_bf16(
            a, *(const short8*)(fb + kk * 512 + 16384), nw_, 0, 0, 0);
        afw[kk] = *(const short8*)(awn + kk * 32);   // refill (consumed next step)
      }
    }

    // --- [B] poll (round-0 asm, bounded): wave 0 spins on 32 per-WG flags ---
    if (tid < 32) {
      const unsigned* fp = flags + tid * 32;
      unsigned fv; int spin = 0;
      do {
        asm volatile("global_load_dword %0, %1, off sc0\n\ts_waitcnt vmcnt(0)"
                     : "=v"(fv)
                     : "v"((unsigned long long)(uintptr_t)fp)
                     : "memory");
      } while (fv < (unsigned)(t + 1) && ++spin < 4096);
    }
    __syncthreads();

    // --- [C] stage h tile into hsT (gll16 sc0, XOR-swizzled; round-0 path) ---
    const unsigned short* hsrc = h_buf + (size_t)(t & 3) * (BB * HH);
#pragma unroll
    for (int i = 0; i < 16; ++i) {
      int b = wv * 16 + i;
      gll16_sc0(hsrc + (size_t)b * 512 + ((lane ^ b) * 8), hsT + b * 512);
    }
    __builtin_amdgcn_s_waitcnt(0);   // h tile resident in LDS
    __syncthreads();

    // --- [D] h-side MFMA from hsT (de-swizzled) + gates ---
    {
      const int hrow = b0 + x;
#pragma unroll
      for (int kk = 0; kk < 16; ++kk) {
        short8 a = *(const short8*)(hsT + (size_t)hrow * 512 +
                                    (size_t)((((kk * 4) + q) ^ hrow) & 63) * 8);
        ar_ = __builtin_amdgcn_mfma_f32_16x16x32_bf16(a, wfrag[0][kk], ar_, 0, 0, 0);
        az_ = __builtin_amdgcn_mfma_f32_16x16x32_bf16(a, wfrag[1][kk], az_, 0, 0, 0);
        nh_ = __builtin_amdgcn_mfma_f32_16x16x32_bf16(a, wfrag[2][kk], nh_, 0, 0, 0);
      }
    }
    float hn[4];
#pragma unroll
    for (int r = 0; r < 4; ++r) {
      float rr = 1.f / (1.f + __expf(-ar_[r]));
      float zz = 1.f / (1.f + __expf(-az_[r]));
      float e2 = __expf(2.f * (nw_[r] + rr * nh_[r]));
      float nn = 1.f - 2.f / (e2 + 1.f);          // tanh
      hn[r] = (1.f - zz) * nn + zz * hp[r];
    }

    // --- [E] publish h_{t+1} (packed dwords); drain; barrier; release flag ---
    unsigned short* hdst = h_buf + (size_t)((t + 1) & 3) * (BB * HH);
#pragma unroll
    for (int r = 0; r < 4; ++r) {
      float ov = __shfl(hn[r], lane ^ 1, 64);
      if ((x & 1) == 0)
        *(unsigned*)(hdst + (size_t)(bq + r) * HH + jx) =
            (unsigned)f2bf(hn[r]) | ((unsigned)f2bf(ov) << 16);
    }
    WAITVM(0);
    __syncthreads();
    if (tid == 0)
      __hip_atomic_store(&flags[w * 32], (unsigned)(t + 2),
                         __ATOMIC_RELEASE, __HIP_MEMORY_SCOPE_AGENT);
    asm volatile("" ::: "memory");

    // --- [F] f32 outputs (post-flag, off the critical path) ---
#pragma unroll
    for (int r = 0; r < 4; ++r) {
      float ov = __shfl(hn[r], lane ^ 1, 64);
      if ((x & 1) == 0)
        *(float2*)(hid_out + ((size_t)t * BB + bq + r) * HH + jx) =
            make_float2(hn[r], ov);
    }
#pragma unroll
    for (int r = 0; r < 4; ++r) hp[r] = hn[r];
  }
}

// ---------------------------------------------------------------------------
// Workspace layout (39.1 MB, NO aliasing — round-3-proven footprint):
//   [0,2MB) G | [2,3.5) Wihb | [3.5,5) Whhb | [5,21) phi | [21,37) awb
//   [37,37.25) hbuf (4 ring slots) | +4KB flags | +64B ctl
extern "C" void kernel_launch(void* const* d_in, const int* in_sizes, int n_in,
                              void* d_out, int out_size, void* d_ws, size_t ws_size,
                              hipStream_t stream) {
  const float* c_inp    = (const float*)d_in[0];
  const float* inp      = (const float*)d_in[1];
  const float* gru_init = (const float*)d_in[2];
  const float* att_init = (const float*)d_in[3];
  const float* Wa = (const float*)d_in[4];
  const float* ba = (const float*)d_in[5];
  const float* Wb = (const float*)d_in[6];
  const float* bvb = (const float*)d_in[7];
  const float* Wk = (const float*)d_in[8];
  const float* bk = (const float*)d_in[9];
  const float* W_ih = (const float*)d_in[10];
  const float* b_ih = (const float*)d_in[11];
  const float* W_hh = (const float*)d_in[12];
  const float* b_hh = (const float*)d_in[13];

  float* out_h = (float*)d_out;                     // hiddens [256,64,512]
  float* out_k = out_h + TS * BB * HH;              // att_k   [256,64,10]
  float* out_w = out_k + TS * BB * KK;              // att_w   [256,64,512]

  char* ws = (char*)d_ws;
  float* G             = (float*)(ws);                          // 1.97 MB
  unsigned short* Wihb = (unsigned short*)(ws + 2097152);       // 1.5 MB
  unsigned short* Whhb = (unsigned short*)(ws + 3670016);       // 1.5 MB
  unsigned short* phi  = (unsigned short*)(ws + 5242880);       // 16 MB
  unsigned short* awb  = (unsigned short*)(ws + 22020096);      // 16 MB
  unsigned short* hbuf = (unsigned short*)(ws + 38797312);      // 256 KB (4 slots)
  unsigned* flags      = (unsigned*)(ws + 39059456);            // 4 KB
  unsigned* ctl        = (unsigned*)(ws + 39063552);            // 64 B

  hipMemsetAsync(flags, 0, 8192, stream);  // flags + ctl
  hipLaunchKernelGGL(k_cast, dim3(3072), dim3(256), 0, stream, W_ih, W_hh, Wihb, Whhb);
  hipLaunchKernelGGL(k_abk, dim3(TS * BB), dim3(64), 0, stream,
                     inp, Wa, ba, Wb, bvb, Wk, bk, G);
  hipLaunchKernelGGL(k_cumsum, dim3(BB), dim3(256), 0, stream, G, att_init, out_k);
  hipLaunchKernelGGL(k_phi, dim3(TS, BB), dim3(256), 0, stream, G, out_k, phi);
  hipLaunchKernelGGL(k_attw, dim3(8, 4, BB), dim3(256), 0, stream, c_inp, phi, out_w, awb);
  hipLaunchKernelGGL(k_seq, dim3(256), dim3(256), 0, stream,
                     awb, Wihb, Whhb, gru_init, b_ih, b_hh, hbuf, flags, ctl, out_h);
}

// Round 6
// 1763.572 us; speedup vs baseline: 409.9477x; 45.8100x over previous
//
#include <hip/hip_runtime.h>
#include <stdint.h>

// Problem dims
#define TS  256
#define CTS 512
#define BB  64
#define HH  512
#define KK  10

typedef short short8 __attribute__((ext_vector_type(8)));
typedef float floatx4 __attribute__((ext_vector_type(4)));

__device__ __forceinline__ unsigned short f2bf(float f) {
  unsigned u = __float_as_uint(f);
  unsigned r = (u + 0x7fffu + ((u >> 16) & 1u)) >> 16;  // RNE
  return (unsigned short)r;
}

// global -> LDS async, 16 B/lane. LDS dst = base + lane*16 (HW rule).
typedef __attribute__((address_space(1))) const unsigned int gas_u32;
typedef __attribute__((address_space(3))) unsigned int las_u32;
__device__ __forceinline__ void gll16_c(const void* g, void* l) {   // cached (L1 ok)
  __builtin_amdgcn_global_load_lds((gas_u32*)g, (las_u32*)l, 16, 0, 0);
}
__device__ __forceinline__ void gll16_sc0(const void* g, void* l) { // bypass L1, read L2
  __builtin_amdgcn_global_load_lds((gas_u32*)g, (las_u32*)l, 16, 0, 1);
}

// ---------------------------------------------------------------------------
// K1: Wcat [2048][1024] bf16.
// Row groups of 512: g0 = r-gate [W_hh_r | W_ih_r]; g1 = z-gate [W_hh_z | W_ih_z];
// g2 = i_n [0 | W_ih_n]; g3 = h_n [W_hh_n | 0]. (n = tanh(i_n + r*h_n) needs the split)
__global__ void k_wcat(const float* __restrict__ W_ih, const float* __restrict__ W_hh,
                       unsigned short* __restrict__ Wcat) {
  int idx = blockIdx.x * 256 + threadIdx.x;  // 2048*1024 total
  int r = idx >> 10, c = idx & 1023;
  int g = r >> 9, j = r & 511;
  float v;
  if (g == 0)      v = (c < 512) ? W_hh[j * 512 + c]          : W_ih[j * 512 + (c - 512)];
  else if (g == 1) v = (c < 512) ? W_hh[(512 + j) * 512 + c]  : W_ih[(512 + j) * 512 + (c - 512)];
  else if (g == 2) v = (c < 512) ? 0.f                        : W_ih[(1024 + j) * 512 + (c - 512)];
  else             v = (c < 512) ? W_hh[(1024 + j) * 512 + c] : 0.f;
  Wcat[idx] = f2bf(v);
}

// ---------------------------------------------------------------------------
// K2: G[t*64+b][30] = exp(x_t[b] @ {Wa;Wb;Wk}.T + bias). One wave per (t,b) row.
__global__ void k_abk(const float* __restrict__ inp,
                      const float* __restrict__ Wa, const float* __restrict__ ba,
                      const float* __restrict__ Wb, const float* __restrict__ bvb,
                      const float* __restrict__ Wk, const float* __restrict__ bk,
                      float* __restrict__ G) {
  int row = blockIdx.x;                 // t*64 + b
  int lane = threadIdx.x;               // 0..63
  int j = lane & 31, half = lane >> 5;  // j = output idx, half = K-half
  const float* Wrow; float bias;
  if (j < 10)      { Wrow = Wa + j * 512;        bias = ba[j]; }
  else if (j < 20) { Wrow = Wb + (j - 10) * 512; bias = bvb[j - 10]; }
  else if (j < 30) { Wrow = Wk + (j - 20) * 512; bias = bk[j - 20]; }
  else             { Wrow = Wa;                  bias = 0.f; }
  const float4* x4 = (const float4*)(inp + row * 512 + half * 256);
  const float4* w4 = (const float4*)(Wrow + half * 256);
  float acc = 0.f;
#pragma unroll 8
  for (int i = 0; i < 64; ++i) {
    float4 a = x4[i], w = w4[i];
    acc += a.x * w.x + a.y * w.y + a.z * w.z + a.w * w.w;
  }
  acc += __shfl_down(acc, 32, 64);  // fold the two K-halves
  if (lane < 30) G[row * 30 + lane] = __expf(acc + bias);
}

// ---------------------------------------------------------------------------
// K3: k_t cumsum over t for each (b,k) — parallel Hillis-Steele scan per b.
__global__ __launch_bounds__(256) void k_cumsum(
    const float* __restrict__ G, const float* __restrict__ att_init,
    float* __restrict__ out_k) {
  int b = blockIdx.x;       // 64 blocks
  int t = threadIdx.x;      // 256 = TS
  __shared__ float sb[2][256];
  for (int k = 0; k < KK; ++k) {
    float v = G[(t * BB + b) * 30 + 20 + k];
    sb[0][t] = v;
    __syncthreads();
    int src = 0;
#pragma unroll
    for (int d = 1; d < 256; d <<= 1) {
      float add = (t >= d) ? sb[src][t - d] : 0.f;
      float cur = sb[src][t];
      __syncthreads();
      sb[1 - src][t] = cur + add;
      src = 1 - src;
      __syncthreads();
    }
    out_k[(t * BB + b) * KK + k] = att_init[b * KK + k] + sb[src][t];
    __syncthreads();
  }
}

// ---------------------------------------------------------------------------
// K4: phi[b][t][s] = sum_k a*exp(-b*(k_t - s)^2), stored bf16.
__global__ void k_phi(const float* __restrict__ G, const float* __restrict__ attk,
                      unsigned short* __restrict__ phi_bf) {
  int t = blockIdx.x, b = blockIdx.y;
  int row = t * BB + b;
  float a[10], bv[10], kt[10];
#pragma unroll
  for (int k = 0; k < 10; ++k) {
    a[k]  = G[row * 30 + k];
    bv[k] = G[row * 30 + 10 + k];
    kt[k] = attk[row * KK + k];
  }
#pragma unroll
  for (int e = 0; e < 2; ++e) {
    int s = threadIdx.x + e * 256;
    float fs = (float)s;
    float ph = 0.f;
#pragma unroll
    for (int k = 0; k < 10; ++k) {
      float d = kt[k] - fs;
      ph += a[k] * __expf(-bv[k] * d * d);
    }
    phi_bf[(b * TS + t) * CTS + s] = f2bf(ph);
  }
}

// ---------------------------------------------------------------------------
// K5: att_w[t][b][h] = sum_s phi[b][t][s] * c_inp[s][b][h]. Per-b MFMA GEMM.
// t0-FUSED vs round 0: grid (8,64) [h0, b]; the 4 t0-tiles loop INSIDE so each
// c_inp Bt tile is staged into LDS once instead of 4x (c_inp HBM 256->64 MB,
// LDS staging ops /4). MFMA count, output mapping, awb side-write unchanged.
__global__ __launch_bounds__(256) void k_attw(
    const float* __restrict__ c_inp, const unsigned short* __restrict__ phi_bf,
    float* __restrict__ out_w, unsigned short* __restrict__ attw_bf) {
  int h0 = blockIdx.x * 64;
  int b  = blockIdx.y;
  int tid = threadIdx.x;
  int lane = tid & 63, wv = tid >> 6;
  int x = lane & 15, q = lane >> 4;
  __shared__ __align__(16) unsigned short Bt[64 * 40];  // [h_local][s_local], pad 40
  floatx4 acc[4][4];                                    // [t0][mt]
#pragma unroll
  for (int t0 = 0; t0 < 4; ++t0)
#pragma unroll
    for (int m = 0; m < 4; ++m) acc[t0][m] = (floatx4){0.f, 0.f, 0.f, 0.f};
  int s_l = tid >> 3, h8 = (tid & 7) * 8;
  for (int ss = 0; ss < 16; ++ss) {
    int s0 = ss * 32;
    const float* src = c_inp + ((s0 + s_l) * BB + b) * HH + h0 + h8;
    float4 v0 = *(const float4*)src;
    float4 v1 = *(const float4*)(src + 4);
    Bt[(h8 + 0) * 40 + s_l] = f2bf(v0.x);
    Bt[(h8 + 1) * 40 + s_l] = f2bf(v0.y);
    Bt[(h8 + 2) * 40 + s_l] = f2bf(v0.z);
    Bt[(h8 + 3) * 40 + s_l] = f2bf(v0.w);
    Bt[(h8 + 4) * 40 + s_l] = f2bf(v1.x);
    Bt[(h8 + 5) * 40 + s_l] = f2bf(v1.y);
    Bt[(h8 + 6) * 40 + s_l] = f2bf(v1.z);
    Bt[(h8 + 7) * 40 + s_l] = f2bf(v1.w);
    __syncthreads();
    short8 bfrag = *(const short8*)(Bt + (wv * 16 + x) * 40 + q * 8);
#pragma unroll
    for (int t0 = 0; t0 < 4; ++t0)
#pragma unroll
      for (int mt = 0; mt < 4; ++mt) {
        short8 af = *(const short8*)(
            phi_bf + ((size_t)b * TS + t0 * 64 + mt * 16 + x) * CTS + s0 + q * 8);
        acc[t0][mt] = __builtin_amdgcn_mfma_f32_16x16x32_bf16(af, bfrag, acc[t0][mt], 0, 0, 0);
      }
    __syncthreads();
  }
#pragma unroll
  for (int t0 = 0; t0 < 4; ++t0)
#pragma unroll
    for (int mt = 0; mt < 4; ++mt)
#pragma unroll
      for (int r = 0; r < 4; ++r) {
        int t_l = t0 * 64 + mt * 16 + q * 4 + r;   // C/D: row = quad*4+reg
        int row = t_l * BB + b;
        int col = h0 + wv * 16 + x;                // C/D: col = lane&15
        float v = acc[t0][mt][r];
        out_w[row * HH + col] = v;
        attw_bf[row * HH + col] = f2bf(v);
      }
}

// ---------------------------------------------------------------------------
// K6: round-0 k_seq, BYTE-FOR-BYTE (proven: passes, 1400 us). The sync
// skeleton (plain C++ flag store + tid<32 sc0 poll + this exact barrier/
// staging sequence) is an indivisible unit: three reconstructions (per-wave
// flags r3, asm-store skeleton r4, atomic-release r5) all broke flag
// visibility (polls timed out every step; r5's +16 MB WRITE_SIZE = agent-
// release buffer_wbl2 flushing the h ring every step). DO NOT EDIT.
__global__ __launch_bounds__(256, 1) void k_seq(
    const unsigned short* __restrict__ attw_bf, const unsigned short* __restrict__ Wcat,
    const float* __restrict__ gru_init, const float* __restrict__ b_ih,
    const float* __restrict__ b_hh, unsigned short* __restrict__ h_buf,
    unsigned* __restrict__ flags, unsigned* __restrict__ ctl,
    float* __restrict__ hid_out) {
  __shared__ __align__(16) unsigned short hsT[64 * 512];   // h_{t-1} tile (swizzled)
  __shared__ __align__(16) unsigned short awT[64 * 512];   // attw_t tile (swizzled)
  __shared__ float bsum[64];
  __shared__ int sh_slot;
  float* const gbuf = (float*)awT;   // gbuf[2][64][66] aliased (33.8 KB < 64 KB)

  const int tid = threadIdx.x;

  // --- XCD-local slot discovery (device-scope atomics, one-time) ---
  if (tid == 0) {
    unsigned xcc = __builtin_amdgcn_s_getreg(6164) & 0xfu;  // hwreg(HW_REG_XCC_ID,0,4)
    unsigned s = atomicAdd(&ctl[1 + xcc], 1u);
    if (s == 31u) atomicCAS(&ctl[0], 0u, xcc + 1u);         // first full bucket wins
    unsigned ch;
    while ((ch = __hip_atomic_load(&ctl[0], __ATOMIC_RELAXED,
                                   __HIP_MEMORY_SCOPE_AGENT)) == 0u) {}
    sh_slot = (ch - 1u == xcc && s < 32u) ? (int)s : -1;
  }
  __syncthreads();
  const int w = sh_slot;
  if (w < 0) return;  // not a worker

  const int lane = tid & 63, wv = tid >> 6;
  const int x = lane & 15, q = lane >> 4;
  const int kh = wv & 1;    // K-half: 0 = h (K 0..511), 1 = w (K 512..1023)
  const int nh = wv >> 1;   // N-half: 32 gate-rows
  const int j0 = w * 16;

  // Weight B-fragments: rows (nh*2+nt)*512 + j0 + x, K-cols kh*512 + kk*32 + q*8.
  short8 wfrag[2][16];
#pragma unroll
  for (int nt = 0; nt < 2; ++nt) {
    const unsigned short* wr = Wcat + (size_t)((nh * 2 + nt) * 512 + j0 + x) * 1024 + kh * 512;
#pragma unroll
    for (int kk = 0; kk < 16; ++kk)
      wfrag[nt][kk] = *(const short8*)(wr + kk * 32 + q * 8);
  }
  if (tid < 64) {
    int g = tid >> 4, jl = tid & 15, j = j0 + jl;
    float v;
    if (g == 0)      v = b_ih[j] + b_hh[j];
    else if (g == 1) v = b_ih[512 + j] + b_hh[512 + j];
    else if (g == 2) v = b_ih[1024 + j];
    else             v = b_hh[1024 + j];
    bsum[tid] = v;
  }
  __syncthreads();
  const float bias0 = (kh == 0) ? bsum[nh * 32 + x] : 0.f;
  const float bias1 = (kh == 0) ? bsum[nh * 32 + 16 + x] : 0.f;

  // This thread's gate cells: (bo, jl0..+1), (bo+32, jl0..+1)
  const int bo = tid >> 3, jl0 = (tid & 7) * 2;
  float hp[4];
  hp[0] = gru_init[bo * HH + j0 + jl0];
  hp[1] = gru_init[bo * HH + j0 + jl0 + 1];
  hp[2] = gru_init[(bo + 32) * HH + j0 + jl0];
  hp[3] = gru_init[(bo + 32) * HH + j0 + jl0 + 1];

  // Publish init h into slot 0 (plain stores -> XCD L2 via write-through L1).
  {
    unsigned p0 = (unsigned)f2bf(hp[0]) | ((unsigned)f2bf(hp[1]) << 16);
    unsigned p1 = (unsigned)f2bf(hp[2]) | ((unsigned)f2bf(hp[3]) << 16);
    *(unsigned*)(h_buf + bo * HH + j0 + jl0) = p0;
    *(unsigned*)(h_buf + (bo + 32) * HH + j0 + jl0) = p1;
  }
  asm volatile("" ::: "memory");
  __builtin_amdgcn_s_waitcnt(0);   // stores L2-committed
  __syncthreads();
  if (tid == 0) flags[w * 32] = 1u;
  asm volatile("" ::: "memory");

  // Prefetch attw(0) tile into awT (async; XOR-swizzled rows).
#pragma unroll
  for (int i = 0; i < 16; ++i) {
    int b = wv * 16 + i;
    gll16_c(attw_bf + (size_t)b * 512 + ((lane ^ b) * 8), awT + b * 512);
  }

  for (int t = 0; t < TS; ++t) {
    // --- wait for all 32 workers to have published h_{t-1} ---
    if (tid < 32) {
      const unsigned* fp = flags + tid * 32;
      unsigned fv;
      do {
        asm volatile("global_load_dword %0, %1, off sc0\n\ts_waitcnt vmcnt(0)"
                     : "=v"(fv)
                     : "v"((unsigned long long)(uintptr_t)fp)
                     : "memory");
      } while (fv < (unsigned)(t + 1));
    }
    __syncthreads();

    // --- stage h_{t-1} into hsT (sc0: bypass L1, read fresh from XCD L2) ---
    const unsigned short* hsrc = h_buf + (size_t)(t & 3) * (BB * HH);
#pragma unroll
    for (int i = 0; i < 16; ++i) {
      int b = wv * 16 + i;
      gll16_sc0(hsrc + (size_t)b * 512 + ((lane ^ b) * 8), hsT + b * 512);
    }
    __builtin_amdgcn_s_waitcnt(0);   // h tile + attw tile resident in LDS
    __syncthreads();

    // --- MFMA: this wave's K-half against its 2 N-tiles ---
    floatx4 acc[4][2];
#pragma unroll
    for (int m = 0; m < 4; ++m) {
      acc[m][0] = (floatx4){bias0, bias0, bias0, bias0};
      acc[m][1] = (floatx4){bias1, bias1, bias1, bias1};
    }
    const unsigned short* tile = kh ? awT : hsT;
#pragma unroll
    for (int kk = 0; kk < 16; ++kk) {
#pragma unroll
      for (int m = 0; m < 4; ++m) {
        int row = m * 16 + x;
        int ch = ((kk * 4 + q) ^ row) & 63;       // de-swizzle
        short8 a = *(const short8*)(tile + row * 512 + ch * 8);
        acc[m][0] = __builtin_amdgcn_mfma_f32_16x16x32_bf16(a, wfrag[0][kk], acc[m][0], 0, 0, 0);
        acc[m][1] = __builtin_amdgcn_mfma_f32_16x16x32_bf16(a, wfrag[1][kk], acc[m][1], 0, 0, 0);
      }
    }
    __syncthreads();   // all tile reads done -> awT low half reusable as gbuf

    // --- scatter partial pre-activations: gbuf[kh][b][n] ---
    {
      float* gb = gbuf + kh * (64 * 66) ;
#pragma unroll
      for (int m = 0; m < 4; ++m)
#pragma unroll
        for (int nt = 0; nt < 2; ++nt)
#pragma unroll
          for (int r = 0; r < 4; ++r)
            gb[(m * 16 + q * 4 + r) * 66 + nh * 32 + nt * 16 + x] = acc[m][nt][r];
    }
    __syncthreads();

    // --- gates for this thread's 4 cells ---
    unsigned short* hdst = h_buf + (size_t)((t + 1) & 3) * (BB * HH);
    float hn_[4];
#pragma unroll
    for (int e = 0; e < 4; ++e) {
      int b = bo + (e >> 1) * 32, jl = jl0 + (e & 1);
      const float* g0 = gbuf + b * 66;
      const float* g1 = gbuf + 64 * 66 + b * 66;
      float rp = g0[jl]      + g1[jl];
      float zp = g0[16 + jl] + g1[16 + jl];
      float ip = g0[32 + jl] + g1[32 + jl];
      float hn = g0[48 + jl] + g1[48 + jl];
      float r_ = 1.f / (1.f + __expf(-rp));
      float z_ = 1.f / (1.f + __expf(-zp));
      float n_ = tanhf(ip + r_ * hn);
      hn_[e] = (1.f - z_) * n_ + z_ * hp[e];
    }
#pragma unroll
    for (int e = 0; e < 4; ++e) hp[e] = hn_[e];

    // --- outputs + publish h_t (plain stores -> XCD L2) ---
    *(float2*)(hid_out + ((size_t)t * BB + bo) * HH + j0 + jl0) =
        make_float2(hp[0], hp[1]);
    *(float2*)(hid_out + ((size_t)t * BB + bo + 32) * HH + j0 + jl0) =
        make_float2(hp[2], hp[3]);
    {
      unsigned p0 = (unsigned)f2bf(hp[0]) | ((unsigned)f2bf(hp[1]) << 16);
      unsigned p1 = (unsigned)f2bf(hp[2]) | ((unsigned)f2bf(hp[3]) << 16);
      *(unsigned*)(hdst + bo * HH + j0 + jl0) = p0;
      *(unsigned*)(hdst + (bo + 32) * HH + j0 + jl0) = p1;
    }
    asm volatile("" ::: "memory");
    __builtin_amdgcn_s_waitcnt(0);   // publishes L2-committed
    __syncthreads();
    if (tid == 0) flags[w * 32] = (unsigned)(t + 2);
    asm volatile("" ::: "memory");

    // --- prefetch attw(t+1) (async; overlaps everyone's flag wait) ---
    if (t + 1 < TS) {
      const unsigned short* aw = attw_bf + (size_t)(t + 1) * (BB * HH);
#pragma unroll
      for (int i = 0; i < 16; ++i) {
        int b = wv * 16 + i;
        gll16_c(aw + (size_t)b * 512 + ((lane ^ b) * 8), awT + b * 512);
      }
    }
  }
}

// ---------------------------------------------------------------------------
extern "C" void kernel_launch(void* const* d_in, const int* in_sizes, int n_in,
                              void* d_out, int out_size, void* d_ws, size_t ws_size,
                              hipStream_t stream) {
  const float* c_inp    = (const float*)d_in[0];
  const float* inp      = (const float*)d_in[1];
  const float* gru_init = (const float*)d_in[2];
  const float* att_init = (const float*)d_in[3];
  const float* Wa = (const float*)d_in[4];
  const float* ba = (const float*)d_in[5];
  const float* Wb = (const float*)d_in[6];
  const float* bvb = (const float*)d_in[7];
  const float* Wk = (const float*)d_in[8];
  const float* bk = (const float*)d_in[9];
  const float* W_ih = (const float*)d_in[10];
  const float* b_ih = (const float*)d_in[11];
  const float* W_hh = (const float*)d_in[12];
  const float* b_hh = (const float*)d_in[13];

  float* out_h = (float*)d_out;                     // hiddens [256,64,512]
  float* out_k = out_h + TS * BB * HH;              // att_k   [256,64,10]
  float* out_w = out_k + TS * BB * KK;              // att_w   [256,64,512]

  char* ws = (char*)d_ws;
  float* G             = (float*)(ws);                              //  2 MB used
  unsigned short* Wcat = (unsigned short*)(ws + 8388608);           //  4 MB
  unsigned short* phi  = (unsigned short*)(ws + 12582912);          // 16 MB
  unsigned short* awb  = (unsigned short*)(ws + 29360128);          // 16 MB
  unsigned short* hbuf = (unsigned short*)(ws + 46137344);          // 256 KB (4 slots)
  unsigned* flags      = (unsigned*)(ws + 46399488);                //  4 KB
  unsigned* ctl        = (unsigned*)(ws + 46403584);                //  64 B

  hipMemsetAsync(flags, 0, 8192, stream);  // flags + ctl
  hipLaunchKernelGGL(k_wcat, dim3(8192), dim3(256), 0, stream, W_ih, W_hh, Wcat);
  hipLaunchKernelGGL(k_abk, dim3(TS * BB), dim3(64), 0, stream,
                     inp, Wa, ba, Wb, bvb, Wk, bk, G);
  hipLaunchKernelGGL(k_cumsum, dim3(BB), dim3(256), 0, stream, G, att_init, out_k);
  hipLaunchKernelGGL(k_phi, dim3(TS, BB), dim3(256), 0, stream, G, out_k, phi);
  hipLaunchKernelGGL(k_attw, dim3(8, BB), dim3(256), 0, stream, c_inp, phi, out_w, awb);
  hipLaunchKernelGGL(k_seq, dim3(256), dim3(256), 0, stream,
                     awb, Wcat, gru_init, b_ih, b_hh, hbuf, flags, ctl, out_h);
}

// Round 7
// 1538.938 us; speedup vs baseline: 469.7864x; 1.1460x over previous
//
#include <hip/hip_runtime.h>
#include <stdint.h>

// Problem dims
#define TS  256
#define CTS 512
#define BB  64
#define HH  512
#define KK  10

typedef short short8 __attribute__((ext_vector_type(8)));
typedef float floatx4 __attribute__((ext_vector_type(4)));

__device__ __forceinline__ unsigned short f2bf(float f) {
  unsigned u = __float_as_uint(f);
  unsigned r = (u + 0x7fffu + ((u >> 16) & 1u)) >> 16;  // RNE
  return (unsigned short)r;
}

// global -> LDS async, 16 B/lane. LDS dst = base + lane*16 (HW rule).
typedef __attribute__((address_space(1))) const unsigned int gas_u32;
typedef __attribute__((address_space(3))) unsigned int las_u32;
__device__ __forceinline__ void gll16_sc0(const void* g, void* l) { // bypass L1, read L2
  __builtin_amdgcn_global_load_lds((gas_u32*)g, (las_u32*)l, 16, 0, 1);
}

// ---------------------------------------------------------------------------
// K1: Wcat [2048][1024] bf16.
// Row groups of 512: g0 = r-gate [W_hh_r | W_ih_r]; g1 = z-gate [W_hh_z | W_ih_z];
// g2 = i_n [0 | W_ih_n]; g3 = h_n [W_hh_n | 0]. (n = tanh(i_n + r*h_n) needs the split)
__global__ void k_wcat(const float* __restrict__ W_ih, const float* __restrict__ W_hh,
                       unsigned short* __restrict__ Wcat) {
  int idx = blockIdx.x * 256 + threadIdx.x;  // 2048*1024 total
  int r = idx >> 10, c = idx & 1023;
  int g = r >> 9, j = r & 511;
  float v;
  if (g == 0)      v = (c < 512) ? W_hh[j * 512 + c]          : W_ih[j * 512 + (c - 512)];
  else if (g == 1) v = (c < 512) ? W_hh[(512 + j) * 512 + c]  : W_ih[(512 + j) * 512 + (c - 512)];
  else if (g == 2) v = (c < 512) ? 0.f                        : W_ih[(1024 + j) * 512 + (c - 512)];
  else             v = (c < 512) ? W_hh[(1024 + j) * 512 + c] : 0.f;
  Wcat[idx] = f2bf(v);
}

// ---------------------------------------------------------------------------
// K2: G[t*64+b][30] = exp(x_t[b] @ {Wa;Wb;Wk}.T + bias). One wave per (t,b) row.
__global__ void k_abk(const float* __restrict__ inp,
                      const float* __restrict__ Wa, const float* __restrict__ ba,
                      const float* __restrict__ Wb, const float* __restrict__ bvb,
                      const float* __restrict__ Wk, const float* __restrict__ bk,
                      float* __restrict__ G) {
  int row = blockIdx.x;                 // t*64 + b
  int lane = threadIdx.x;               // 0..63
  int j = lane & 31, half = lane >> 5;  // j = output idx, half = K-half
  const float* Wrow; float bias;
  if (j < 10)      { Wrow = Wa + j * 512;        bias = ba[j]; }
  else if (j < 20) { Wrow = Wb + (j - 10) * 512; bias = bvb[j - 10]; }
  else if (j < 30) { Wrow = Wk + (j - 20) * 512; bias = bk[j - 20]; }
  else             { Wrow = Wa;                  bias = 0.f; }
  const float4* x4 = (const float4*)(inp + row * 512 + half * 256);
  const float4* w4 = (const float4*)(Wrow + half * 256);
  float acc = 0.f;
#pragma unroll 8
  for (int i = 0; i < 64; ++i) {
    float4 a = x4[i], w = w4[i];
    acc += a.x * w.x + a.y * w.y + a.z * w.z + a.w * w.w;
  }
  acc += __shfl_down(acc, 32, 64);  // fold the two K-halves
  if (lane < 30) G[row * 30 + lane] = __expf(acc + bias);
}

// ---------------------------------------------------------------------------
// K3: k_t cumsum over t for each (b,k) — parallel Hillis-Steele scan per b.
__global__ __launch_bounds__(256) void k_cumsum(
    const float* __restrict__ G, const float* __restrict__ att_init,
    float* __restrict__ out_k) {
  int b = blockIdx.x;       // 64 blocks
  int t = threadIdx.x;      // 256 = TS
  __shared__ float sb[2][256];
  for (int k = 0; k < KK; ++k) {
    float v = G[(t * BB + b) * 30 + 20 + k];
    sb[0][t] = v;
    __syncthreads();
    int src = 0;
#pragma unroll
    for (int d = 1; d < 256; d <<= 1) {
      float add = (t >= d) ? sb[src][t - d] : 0.f;
      float cur = sb[src][t];
      __syncthreads();
      sb[1 - src][t] = cur + add;
      src = 1 - src;
      __syncthreads();
    }
    out_k[(t * BB + b) * KK + k] = att_init[b * KK + k] + sb[src][t];
    __syncthreads();
  }
}

// ---------------------------------------------------------------------------
// K4: phi[b][t][s] = sum_k a*exp(-b*(k_t - s)^2), stored bf16.
__global__ void k_phi(const float* __restrict__ G, const float* __restrict__ attk,
                      unsigned short* __restrict__ phi_bf) {
  int t = blockIdx.x, b = blockIdx.y;
  int row = t * BB + b;
  float a[10], bv[10], kt[10];
#pragma unroll
  for (int k = 0; k < 10; ++k) {
    a[k]  = G[row * 30 + k];
    bv[k] = G[row * 30 + 10 + k];
    kt[k] = attk[row * KK + k];
  }
#pragma unroll
  for (int e = 0; e < 2; ++e) {
    int s = threadIdx.x + e * 256;
    float fs = (float)s;
    float ph = 0.f;
#pragma unroll
    for (int k = 0; k < 10; ++k) {
      float d = kt[k] - fs;
      ph += a[k] * __expf(-bv[k] * d * d);
    }
    phi_bf[(b * TS + t) * CTS + s] = f2bf(ph);
  }
}

// ---------------------------------------------------------------------------
// K5: att_w[t][b][h] = sum_s phi[b][t][s] * c_inp[s][b][h]. Per-b MFMA GEMM.
// t0-FUSED (round-6, passed): grid (8,64); 4 t0-tiles loop inside so each
// c_inp Bt tile is staged once instead of 4x.
__global__ __launch_bounds__(256) void k_attw(
    const float* __restrict__ c_inp, const unsigned short* __restrict__ phi_bf,
    float* __restrict__ out_w, unsigned short* __restrict__ attw_bf) {
  int h0 = blockIdx.x * 64;
  int b  = blockIdx.y;
  int tid = threadIdx.x;
  int lane = tid & 63, wv = tid >> 6;
  int x = lane & 15, q = lane >> 4;
  __shared__ __align__(16) unsigned short Bt[64 * 40];  // [h_local][s_local], pad 40
  floatx4 acc[4][4];                                    // [t0][mt]
#pragma unroll
  for (int t0 = 0; t0 < 4; ++t0)
#pragma unroll
    for (int m = 0; m < 4; ++m) acc[t0][m] = (floatx4){0.f, 0.f, 0.f, 0.f};
  int s_l = tid >> 3, h8 = (tid & 7) * 8;
  for (int ss = 0; ss < 16; ++ss) {
    int s0 = ss * 32;
    const float* src = c_inp + ((s0 + s_l) * BB + b) * HH + h0 + h8;
    float4 v0 = *(const float4*)src;
    float4 v1 = *(const float4*)(src + 4);
    Bt[(h8 + 0) * 40 + s_l] = f2bf(v0.x);
    Bt[(h8 + 1) * 40 + s_l] = f2bf(v0.y);
    Bt[(h8 + 2) * 40 + s_l] = f2bf(v0.z);
    Bt[(h8 + 3) * 40 + s_l] = f2bf(v0.w);
    Bt[(h8 + 4) * 40 + s_l] = f2bf(v1.x);
    Bt[(h8 + 5) * 40 + s_l] = f2bf(v1.y);
    Bt[(h8 + 6) * 40 + s_l] = f2bf(v1.z);
    Bt[(h8 + 7) * 40 + s_l] = f2bf(v1.w);
    __syncthreads();
    short8 bfrag = *(const short8*)(Bt + (wv * 16 + x) * 40 + q * 8);
#pragma unroll
    for (int t0 = 0; t0 < 4; ++t0)
#pragma unroll
      for (int mt = 0; mt < 4; ++mt) {
        short8 af = *(const short8*)(
            phi_bf + ((size_t)b * TS + t0 * 64 + mt * 16 + x) * CTS + s0 + q * 8);
        acc[t0][mt] = __builtin_amdgcn_mfma_f32_16x16x32_bf16(af, bfrag, acc[t0][mt], 0, 0, 0);
      }
    __syncthreads();
  }
#pragma unroll
  for (int t0 = 0; t0 < 4; ++t0)
#pragma unroll
    for (int mt = 0; mt < 4; ++mt)
#pragma unroll
      for (int r = 0; r < 4; ++r) {
        int t_l = t0 * 64 + mt * 16 + q * 4 + r;   // C/D: row = quad*4+reg
        int row = t_l * BB + b;
        int col = h0 + wv * 16 + x;                // C/D: col = lane&15
        float v = acc[t0][mt][r];
        out_w[row * HH + col] = v;
        attw_bf[row * HH + col] = f2bf(v);
      }
}

// ---------------------------------------------------------------------------
// K6: persistent GRU. SYNC SKELETON = round-0, VERBATIM (proven; r3/r4/r5
// reconstructions all broke flag visibility — per-WG flags 128 B apart, plain
// C++ dword flag store by tid0 after s_waitcnt(0)+__syncthreads, tid<32
// unbounded sc0 poll, gll16_sc0 h-staging into XOR-swizzled hsT).
// COMPUTE = gang decomposition (r3/r5-pass-verified blocks): wave wv owns
// batches [16wv,16wv+16), WG owns j [16w,16w+16). Gates in-lane
// (C/D row=q*4+r -> batch, col=x -> j). vs round-0 per step: no gbuf
// scatter/gather (-2 barriers, -conflicts), 384 vs 512 MFMA (no zero-blocks),
// 16 vs 64 ds_reads, and the w-side (attw @ W_ih, h-independent, Swih LDS
// B-frags + reg-prefetched A-frags) runs BEFORE the poll, overlapping flag
// propagation. No awT staging at all.
__global__ __launch_bounds__(256, 1) void k_seq(
    const unsigned short* __restrict__ attw_bf, const unsigned short* __restrict__ Wcat,
    const float* __restrict__ gru_init, const float* __restrict__ b_ih,
    const float* __restrict__ b_hh, unsigned short* __restrict__ h_buf,
    unsigned* __restrict__ flags, unsigned* __restrict__ ctl,
    float* __restrict__ hid_out) {
  // 112 KB LDS -> 1 WG/CU so all 256 WGs co-reside (handshake needs it).
  __shared__ __align__(16) unsigned short hsT[64 * 512];  // 64 KB h tile (swizzled)
  __shared__ __align__(16) unsigned short Swih[24576];    // 48 KB W_ih frags
  __shared__ int sh_slot;
  const int tid = threadIdx.x;

  // --- XCD-local slot discovery (round-0 VERBATIM) ---
  if (tid == 0) {
    unsigned xcc = __builtin_amdgcn_s_getreg(6164) & 0xfu;  // hwreg(HW_REG_XCC_ID,0,4)
    unsigned s = atomicAdd(&ctl[1 + xcc], 1u);
    if (s == 31u) atomicCAS(&ctl[0], 0u, xcc + 1u);         // first full bucket wins
    unsigned ch;
    while ((ch = __hip_atomic_load(&ctl[0], __ATOMIC_RELAXED,
                                   __HIP_MEMORY_SCOPE_AGENT)) == 0u) {}
    sh_slot = (ch - 1u == xcc && s < 32u) ? (int)s : -1;
  }
  __syncthreads();
  const int w = sh_slot;
  if (w < 0) return;  // not a worker

  const int lane = tid & 63, wv = tid >> 6;
  const int x = lane & 15, q = lane >> 4;
  const int j0 = w * 16;          // this WG's 16 h-columns
  const int b0 = wv * 16;         // this wave's gang: 16 batches
  const int bq = b0 + q * 4;      // C/D row base for this lane
  const int jx = j0 + x;

  // --- stage W_ih frags (gates r,z,i_n; Wcat K-cols 512..1023) into Swih,
  //     frag-major (r3-verified): short addr = fidx*8,
  //     fidx = ((g*16+kk)*4+qq)*16 + jl.
#pragma unroll
  for (int i = 0; i < 12; ++i) {
    int fidx = i * 256 + tid;          // 0..3071
    int jl = fidx & 15;
    int rest = fidx >> 4;              // (g*16+kk)*4+qq
    int qq = rest & 3;
    int rest2 = rest >> 2;             // g*16+kk
    int kk = rest2 & 15, g = rest2 >> 4;
    *(short8*)(Swih + (size_t)fidx * 8) =
        *(const short8*)(Wcat + (size_t)(g * 512 + j0 + jl) * 1024 + 512 + kk * 32 + qq * 8);
  }

  // --- W_hh B-frags into regs: gates r(g0), z(g1), h_n(g3); Wcat K-cols 0..511 ---
  short8 wfrag[3][16];
#pragma unroll
  for (int gi = 0; gi < 3; ++gi) {
    const int g = (gi == 2) ? 3 : gi;
    const unsigned short* wr = Wcat + (size_t)(g * 512 + jx) * 1024 + q * 8;
#pragma unroll
    for (int kk = 0; kk < 16; ++kk)
      wfrag[gi][kk] = *(const short8*)(wr + kk * 32);
  }
  const float biasR  = b_ih[jx] + b_hh[jx];
  const float biasZ  = b_ih[512 + jx] + b_hh[512 + jx];
  const float biasNW = b_ih[1024 + jx];
  const float biasNH = b_hh[1024 + jx];

  float hp[4];
#pragma unroll
  for (int r = 0; r < 4; ++r) hp[r] = gru_init[(size_t)(bq + r) * HH + jx];

  // --- publish h_0 (plain packed-dword stores, r5-verified packing), then
  //     round-0 VERBATIM drain/barrier/flag ---
#pragma unroll
  for (int r = 0; r < 4; ++r) {
    float ov = __shfl(hp[r], lane ^ 1, 64);
    if ((x & 1) == 0)
      *(unsigned*)(h_buf + (size_t)(bq + r) * HH + jx) =
          (unsigned)f2bf(hp[r]) | ((unsigned)f2bf(ov) << 16);
  }
  asm volatile("" ::: "memory");
  __builtin_amdgcn_s_waitcnt(0);   // stores L2-committed
  __syncthreads();                 // also covers Swih staging
  if (tid == 0) flags[w * 32] = 1u;
  asm volatile("" ::: "memory");

  // --- attw(0) A-frags prefetch (plain loads; L1/L2) ---
  short8 afw[16];
  {
    const unsigned short* ap = attw_bf + (size_t)(b0 + x) * HH + q * 8;
#pragma unroll
    for (int kk = 0; kk < 16; ++kk) afw[kk] = *(const short8*)(ap + kk * 32);
  }

#pragma unroll 1
  for (int t = 0; t < TS; ++t) {
    // --- [A] w-side GEMM (h-independent) + afw refill for t+1 ---
    floatx4 ar_ = {biasR, biasR, biasR, biasR};
    floatx4 az_ = {biasZ, biasZ, biasZ, biasZ};
    floatx4 nw_ = {biasNW, biasNW, biasNW, biasNW};
    floatx4 nh_ = {biasNH, biasNH, biasNH, biasNH};
    {
      int tn = (t + 1 < TS) ? t + 1 : t;
      const unsigned short* awn = attw_bf + ((size_t)tn * BB + b0 + x) * HH + q * 8;
      const unsigned short* fb = Swih + (size_t)q * 128 + x * 8;
#pragma unroll
      for (int kk = 0; kk < 16; ++kk) {
        short8 a = afw[kk];
        ar_ = __builtin_amdgcn_mfma_f32_16x16x32_bf16(
            a, *(const short8*)(fb + kk * 512), ar_, 0, 0, 0);
        az_ = __builtin_amdgcn_mfma_f32_16x16x32_bf16(
            a, *(const short8*)(fb + kk * 512 + 8192), az_, 0, 0, 0);
        nw_ = __builtin_amdgcn_mfma_f32_16x16x32_bf16(
            a, *(const short8*)(fb + kk * 512 + 16384), nw_, 0, 0, 0);
        afw[kk] = *(const short8*)(awn + kk * 32);   // refill (consumed next step)
      }
    }

    // --- [B] poll: round-0 VERBATIM (unbounded, tid<32, sc0) ---
    if (tid < 32) {
      const unsigned* fp = flags + tid * 32;
      unsigned fv;
      do {
        asm volatile("global_load_dword %0, %1, off sc0\n\ts_waitcnt vmcnt(0)"
                     : "=v"(fv)
                     : "v"((unsigned long long)(uintptr_t)fp)
                     : "memory");
      } while (fv < (unsigned)(t + 1));
    }
    __syncthreads();

    // --- [C] stage h_{t-1} into hsT: round-0 VERBATIM ---
    const unsigned short* hsrc = h_buf + (size_t)(t & 3) * (BB * HH);
#pragma unroll
    for (int i = 0; i < 16; ++i) {
      int b = wv * 16 + i;
      gll16_sc0(hsrc + (size_t)b * 512 + ((lane ^ b) * 8), hsT + b * 512);
    }
    __builtin_amdgcn_s_waitcnt(0);   // h tile resident in LDS
    __syncthreads();

    // --- [D] h-side MFMA from hsT (de-swizzled; r5-verified addressing) ---
    {
      const int hrow = b0 + x;
#pragma unroll
      for (int kk = 0; kk < 16; ++kk) {
        short8 a = *(const short8*)(hsT + (size_t)hrow * 512 +
                                    (size_t)(((kk * 4 + q) ^ hrow) & 63) * 8);
        ar_ = __builtin_amdgcn_mfma_f32_16x16x32_bf16(a, wfrag[0][kk], ar_, 0, 0, 0);
        az_ = __builtin_amdgcn_mfma_f32_16x16x32_bf16(a, wfrag[1][kk], az_, 0, 0, 0);
        nh_ = __builtin_amdgcn_mfma_f32_16x16x32_bf16(a, wfrag[2][kk], nh_, 0, 0, 0);
      }
    }

    // --- gates: everything for (b,j) lives in this lane (r3-verified) ---
    float hn[4];
#pragma unroll
    for (int r = 0; r < 4; ++r) {
      float rr = 1.f / (1.f + __expf(-ar_[r]));
      float zz = 1.f / (1.f + __expf(-az_[r]));
      float e2 = __expf(2.f * (nw_[r] + rr * nh_[r]));
      float nn = 1.f - 2.f / (e2 + 1.f);          // tanh
      hn[r] = (1.f - zz) * nn + zz * hp[r];
    }

    // --- [E] publish h_{t+1} (plain packed dwords) + round-0 VERBATIM
    //     drain/barrier/flag ---
    unsigned short* hdst = h_buf + (size_t)((t + 1) & 3) * (BB * HH);
#pragma unroll
    for (int r = 0; r < 4; ++r) {
      float ov = __shfl(hn[r], lane ^ 1, 64);
      if ((x & 1) == 0)
        *(unsigned*)(hdst + (size_t)(bq + r) * HH + jx) =
            (unsigned)f2bf(hn[r]) | ((unsigned)f2bf(ov) << 16);
    }
    asm volatile("" ::: "memory");
    __builtin_amdgcn_s_waitcnt(0);   // publishes L2-committed
    __syncthreads();
    if (tid == 0) flags[w * 32] = (unsigned)(t + 2);
    asm volatile("" ::: "memory");

    // --- [F] f32 outputs (post-flag, off the critical path) ---
#pragma unroll
    for (int r = 0; r < 4; ++r) {
      float ov = __shfl(hn[r], lane ^ 1, 64);
      if ((x & 1) == 0)
        *(float2*)(hid_out + ((size_t)t * BB + bq + r) * HH + jx) =
            make_float2(hn[r], ov);
    }
#pragma unroll
    for (int r = 0; r < 4; ++r) hp[r] = hn[r];
  }
}

// ---------------------------------------------------------------------------
extern "C" void kernel_launch(void* const* d_in, const int* in_sizes, int n_in,
                              void* d_out, int out_size, void* d_ws, size_t ws_size,
                              hipStream_t stream) {
  const float* c_inp    = (const float*)d_in[0];
  const float* inp      = (const float*)d_in[1];
  const float* gru_init = (const float*)d_in[2];
  const float* att_init = (const float*)d_in[3];
  const float* Wa = (const float*)d_in[4];
  const float* ba = (const float*)d_in[5];
  const float* Wb = (const float*)d_in[6];
  const float* bvb = (const float*)d_in[7];
  const float* Wk = (const float*)d_in[8];
  const float* bk = (const float*)d_in[9];
  const float* W_ih = (const float*)d_in[10];
  const float* b_ih = (const float*)d_in[11];
  const float* W_hh = (const float*)d_in[12];
  const float* b_hh = (const float*)d_in[13];

  float* out_h = (float*)d_out;                     // hiddens [256,64,512]
  float* out_k = out_h + TS * BB * HH;              // att_k   [256,64,10]
  float* out_w = out_k + TS * BB * KK;              // att_w   [256,64,512]

  char* ws = (char*)d_ws;
  float* G             = (float*)(ws);                              //  2 MB used
  unsigned short* Wcat = (unsigned short*)(ws + 8388608);           //  4 MB
  unsigned short* phi  = (unsigned short*)(ws + 12582912);          // 16 MB
  unsigned short* awb  = (unsigned short*)(ws + 29360128);          // 16 MB
  unsigned short* hbuf = (unsigned short*)(ws + 46137344);          // 256 KB (4 slots)
  unsigned* flags      = (unsigned*)(ws + 46399488);                //  4 KB
  unsigned* ctl        = (unsigned*)(ws + 46403584);                //  64 B

  hipMemsetAsync(flags, 0, 8192, stream);  // flags + ctl
  hipLaunchKernelGGL(k_wcat, dim3(8192), dim3(256), 0, stream, W_ih, W_hh, Wcat);
  hipLaunchKernelGGL(k_abk, dim3(TS * BB), dim3(64), 0, stream,
                     inp, Wa, ba, Wb, bvb, Wk, bk, G);
  hipLaunchKernelGGL(k_cumsum, dim3(BB), dim3(256), 0, stream, G, att_init, out_k);
  hipLaunchKernelGGL(k_phi, dim3(TS, BB), dim3(256), 0, stream, G, out_k, phi);
  hipLaunchKernelGGL(k_attw, dim3(8, BB), dim3(256), 0, stream, c_inp, phi, out_w, awb);
  hipLaunchKernelGGL(k_seq, dim3(256), dim3(256), 0, stream,
                     awb, Wcat, gru_init, b_ih, b_hh, hbuf, flags, ctl, out_h);
}